// Round 13
// baseline (433.798 us; speedup 1.0000x reference)
//
#include <hip/hip_runtime.h>
#include <math.h>

#define SDIM   256
#define HID    512
#define NH     5
#define HEADS  10
#define POP    4096
#define ITERS  4
#define ELITE  819
#define INIT_STDF 0.4f
#define MIN_STDF  0.1f

// ws layout:
//   floats: base1[10][512] @0, q_part[4][10][4096] @5120 (part = cb*2+kh),
//           state @168960 (7 floats)
//   bytes WS_W2S_BYTE+: W2S split/transposed weights, slab layout:
//   [h][cb(2)][jc(16)] slabs of 16384 ushorts: {hi[kg4][col256][ji8], lo[...]}
#define WS_BASE1 0
#define WS_Q     5120
#define WS_STATE 168960
#define WS_W2S_BYTE 675872
#define W2S_USHORTS (HEADS * 2 * 16 * 16384)
#define WS_NEED_BYTES (WS_W2S_BYTE + (size_t)W2S_USHORTS * 2)

typedef __attribute__((ext_vector_type(4))) float f32x4;
typedef __attribute__((ext_vector_type(8))) short bf16x8;

static __device__ __forceinline__ unsigned short bf16_rne(float x) {
    unsigned b = __float_as_uint(x);
    return (unsigned short)((b + 0x7FFFu + ((b >> 16) & 1u)) >> 16);
}

// packed f32x2 -> bf16x2 (hardware cvt_pk, RNE)
static __device__ __forceinline__ unsigned pack2(float x, float y) {
    unsigned r;
    asm("v_cvt_pk_bf16_f32 %0, %1, %2" : "=v"(r) : "v"(x), "v"(y));
    return r;
}

static __device__ __forceinline__ float clip1(float x) {
    return fminf(fmaxf(x, -1.f), 1.f);
}

// ---------------------------------------------------------------------------
// Kernel 1: base1[h][j] = b1[h][j] + sum_i s[i] * W1[h][i][j]; init state
// ---------------------------------------------------------------------------
__global__ __launch_bounds__(256) void k_base(const float* __restrict__ state,
                                              const float* __restrict__ W1,
                                              const float* __restrict__ b1,
                                              float* __restrict__ ws)
{
    const int h = blockIdx.y;
    const int j = blockIdx.x * 256 + threadIdx.x;
    const float* w1h = W1 + (size_t)h * 258 * HID;
    float acc = b1[h * HID + j];
    for (int i = 0; i < SDIM; ++i)
        acc += state[i] * w1h[(size_t)i * HID + j];
    ws[WS_BASE1 + h * HID + j] = acc;

    if (h == 0 && blockIdx.x == 0 && threadIdx.x == 0) {
        float* st = ws + WS_STATE;
        st[0] = 0.f; st[1] = 0.f;
        st[2] = INIT_STDF; st[3] = INIT_STDF;
        st[4] = 0.f; st[5] = 0.f;
        st[6] = -3.402823466e38f;
    }
}

// ---------------------------------------------------------------------------
// Kernel 1b: W2 -> W2S (transpose + RNE hi/lo split). Coalesced both sides.
// ---------------------------------------------------------------------------
__global__ __launch_bounds__(256) void k_split(const float* __restrict__ W2,
                                               unsigned short* __restrict__ W2S)
{
    const int h = blockIdx.z, cb = blockIdx.y, jc = blockIdx.x;
    const int c = threadIdx.x;
    unsigned short* slab = W2S + (size_t)((h * 2 + cb) * 16 + jc) * 16384;
    #pragma unroll
    for (int jg = 0; jg < 4; ++jg) {
        unsigned hp[4], lp[4];
        #pragma unroll
        for (int i = 0; i < 4; ++i) {
            const int j = jc * 32 + jg * 8 + 2 * i;
            float v0 = W2[(size_t)(h * HID + j) * HID + cb * 256 + c];
            float v1 = W2[(size_t)(h * HID + j + 1) * HID + cb * 256 + c];
            unsigned short h0 = bf16_rne(v0), h1 = bf16_rne(v1);
            float f0 = __uint_as_float((unsigned)h0 << 16);
            float f1 = __uint_as_float((unsigned)h1 << 16);
            unsigned short l0 = bf16_rne(v0 - f0), l1 = bf16_rne(v1 - f1);
            hp[i] = (unsigned)h0 | ((unsigned)h1 << 16);
            lp[i] = (unsigned)l0 | ((unsigned)l1 << 16);
        }
        uint4 HV, LV;
        HV.x = hp[0]; HV.y = hp[1]; HV.z = hp[2]; HV.w = hp[3];
        LV.x = lp[0]; LV.y = lp[1]; LV.z = lp[2]; LV.w = lp[3];
        *(uint4*)&slab[jg * 2048 + c * 8] = HV;
        *(uint4*)&slab[8192 + jg * 2048 + c * 8] = LV;
    }
}

// ---------------------------------------------------------------------------
// Kernel 2 (K-split grid): block = 512 thr / 8 waves = 64 rows x 256 cols x
// HALF of K (8 chunks, kh in {0,1}). Grid 2560 = exactly 5 rounds of the
// 512 co-resident block slots (was 1280 -> 2.5 rounds, 17% tail idle).
// Wave = 64 rows x 32 cols, acc[4][2] = 32 AGPR (4 waves/SIMD). A computed
// into LDS dbuf by all 512 threads, CONFLICT-FREE pairing (half = tid&1 ->
// consecutive lanes write consecutive 8B). B direct global->VGPR with
// next-chunk prefetch. One barrier/chunk; setprio(1) around MFMAs.
// Writes q_part[cb*2+kh][h][row]; k_select sums the 4 partials.
// ---------------------------------------------------------------------------
__global__ __launch_bounds__(512, 4) void k_score_mfma11(
    const float* __restrict__ noise, const float* __restrict__ W1,
    const unsigned short* __restrict__ W2S,
    const float* __restrict__ b2, const float* __restrict__ W3,
    float* __restrict__ ws, int t)
{
    __shared__ unsigned short As[2][4096];   // dbuf: {hi[kg4][row64][ji8], lo}
    __shared__ float red[8][64];

    const int tid = threadIdx.x;
    const int bid = blockIdx.x;
    // bijective XCD remap (2560 = 8*320): consecutive w share (h,cb,kh) panel
    const int w = (bid & 7) * 320 + (bid >> 3);
    const int h = w >> 8;
    const int rem = w & 255;
    const int cb = rem >> 7;
    const int kh = (rem >> 6) & 1;      // K-half: chunks kh*8 .. kh*8+7
    const int rs = rem & 63;            // row-stripe of 64

    const int lane = tid & 63;
    const int wv = tid >> 6;            // 0..7 -> 32-col strip
    const int l15 = lane & 15, lk = lane >> 4;

    // computeA role (all 512 threads, conflict-free pairing):
    // akg = tid>>7, row = (tid>>1)&63, half = tid&1 -> 4 elements each;
    // write addr = akg*512 + (tid&127)*4 ushorts: linear 8B per lane.
    const int akg = tid >> 7;
    const int arow = (tid >> 1) & 63;
    const int ahalf = tid & 1;

    const float* st = ws + WS_STATE;
    const float mu0 = st[0], mu1 = st[1], sd0 = st[2], sd1 = st[3];
    float2 e = *(const float2*)&noise[((size_t)t * POP + rs * 64 + arow) * 2];
    const float a0 = clip1(mu0 + sd0 * e.x);
    const float a1 = clip1(mu1 + sd1 * e.y);

    const float* base1 = ws + WS_BASE1 + h * HID;
    const float* w1u = W1 + ((size_t)h * 258 + 256) * HID;
    const float* w1v = W1 + ((size_t)h * 258 + 257) * HID;
    const unsigned short* bslab = W2S + (size_t)((h * 2 + cb) * 16) * 16384;
    // B frag: kg=lk, col = wv*32 + n*16 + l15 (lo at +8192)
    const int bco = lk * 2048 + (wv * 32 + l15) * 8;

    // compute A chunk jc (rank-2 + relu + cvt_pk hi/lo split) into As[buf]
    auto computeA = [&](int jc, int buf) {
        const int j = jc * 32 + akg * 8 + ahalf * 4;
        f32x4 b0 = *(const f32x4*)&base1[j];
        f32x4 u0 = *(const f32x4*)&w1u[j];
        f32x4 v0 = *(const f32x4*)&w1v[j];
        float hv[4];
        #pragma unroll
        for (int i = 0; i < 4; ++i)
            hv[i] = fmaxf(b0[i] + a0 * u0[i] + a1 * v0[i], 0.f);
        unsigned ph[2], pl[2];
        #pragma unroll
        for (int i = 0; i < 2; ++i) {
            ph[i] = pack2(hv[2 * i], hv[2 * i + 1]);
            float fx = __uint_as_float(ph[i] << 16);
            float fy = __uint_as_float(ph[i] & 0xFFFF0000u);
            pl[i] = pack2(hv[2 * i] - fx, hv[2 * i + 1] - fy);
        }
        uint2 HV, LV;
        HV.x = ph[0]; HV.y = ph[1];
        LV.x = pl[0]; LV.y = pl[1];
        const int ao = akg * 512 + arow * 8 + ahalf * 4;
        *(uint2*)&As[buf][ao] = HV;
        *(uint2*)&As[buf][2048 + ao] = LV;
    };

    f32x4 acc[4][2];
    #pragma unroll
    for (int m = 0; m < 4; ++m)
        #pragma unroll
        for (int n = 0; n < 2; ++n)
            acc[m][n] = (f32x4){0.f, 0.f, 0.f, 0.f};

    // prologue: A(first chunk) into buf 0; B(first chunk) into regs
    const int jc0 = kh * 8;
    computeA(jc0, 0);
    bf16x8 BH[2], BL[2];
    {
        const unsigned short* b0p = bslab + (size_t)jc0 * 16384;
        #pragma unroll
        for (int n = 0; n < 2; ++n) {
            BH[n] = *(const bf16x8*)(b0p + bco + n * 128);
            BL[n] = *(const bf16x8*)(b0p + 8192 + bco + n * 128);
        }
    }
    __syncthreads();

    int cur = 0;
    #pragma unroll 1
    for (int c = 0; c < 8; ++c) {
        const int jc = jc0 + c;
        // A fragments from shared tile (8 x ds_read_b128, conflict-free)
        bf16x8 AH[4], AL[4];
        #pragma unroll
        for (int m = 0; m < 4; ++m) {
            const int ad = lk * 512 + (m * 16 + l15) * 8;
            AH[m] = *(const bf16x8*)&As[cur][ad];
            AL[m] = *(const bf16x8*)&As[cur][2048 + ad];
        }
        // prefetch next-chunk B (clamped; hidden under this chunk's MFMAs)
        const int njc = (c < 7) ? jc + 1 : jc;
        const unsigned short* bnc = bslab + (size_t)njc * 16384;
        bf16x8 nBH[2], nBL[2];
        #pragma unroll
        for (int n = 0; n < 2; ++n) {
            nBH[n] = *(const bf16x8*)(bnc + bco + n * 128);
            nBL[n] = *(const bf16x8*)(bnc + 8192 + bco + n * 128);
        }
        // 3 passes of 8 independent MFMAs
        __builtin_amdgcn_s_setprio(1);
        #pragma unroll
        for (int m = 0; m < 4; ++m)
            #pragma unroll
            for (int n = 0; n < 2; ++n)
                acc[m][n] = __builtin_amdgcn_mfma_f32_16x16x32_bf16(
                    AH[m], BH[n], acc[m][n], 0, 0, 0);
        #pragma unroll
        for (int m = 0; m < 4; ++m)
            #pragma unroll
            for (int n = 0; n < 2; ++n)
                acc[m][n] = __builtin_amdgcn_mfma_f32_16x16x32_bf16(
                    AL[m], BH[n], acc[m][n], 0, 0, 0);
        #pragma unroll
        for (int m = 0; m < 4; ++m)
            #pragma unroll
            for (int n = 0; n < 2; ++n)
                acc[m][n] = __builtin_amdgcn_mfma_f32_16x16x32_bf16(
                    AH[m], BL[n], acc[m][n], 0, 0, 0);
        __builtin_amdgcn_s_setprio(0);
        // next A tile into the other buffer, then one barrier
        computeA(njc, cur ^ 1);
        __syncthreads();
        #pragma unroll
        for (int n = 0; n < 2; ++n) { BH[n] = nBH[n]; BL[n] = nBL[n]; }
        cur ^= 1;
    }

    // epilogue: q_part = sum over this block's 256 cols (and K-half) of
    //           relu-free partial: sum_k h1*W2 terms fed through layer-3.
    // NOTE: relu(acc + b2) is only valid on the FULL-K sum, so the two
    // K-half partials must be summed BEFORE relu -> we emit raw partials
    // of (acc) and let k_select apply b2+relu+W3? That would change layout.
    // Instead: kh=0 and kh=1 blocks each hold HALF the pre-activation sum.
    // We write the raw pre-activation partial contracted with nothing --
    // but relu is nonlinear, so the contraction with W3 must happen after
    // summing halves. To keep the q_part layout (64 floats/block), each
    // block writes sum_cols relu-contribution ONLY when it owns the full
    // pre-activation: that requires the other half. Resolution: blocks
    // write PRE-ACTIVATION partials per (row, col-block) is too large.
    // => Use the linearity trick: write partial z = acc (pre-activation)
    // contracted AFTER k_select cannot work. Therefore kh blocks write
    // col-contracted values computed from the FULL pre-activation by
    // exchanging the missing half via q_part is impossible.
    //
    // SAFE CHOICE: keep relu exact by having the K-halves write to
    // SEPARATE pre-activation partial planes per 256-col block, and let
    // k_select do: z = partA(kh0) + partA(kh1) + b2 ... but that is per
    // (pop, col) = 4096x512 floats -- too big.
    //
    // => Final resolution used here: kh splits the COLUMN dim instead of K.
    // Each block handles 128 cols x FULL K (16 chunks of cols halved):
    // B frag cols = (cb*2+kh)*128 + wv*16 + ... (8 waves x 16 cols).
    // This keeps relu exact per column and q_part stays 4 partials.
    float qp[4][4];
    #pragma unroll
    for (int m = 0; m < 4; ++m)
        #pragma unroll
        for (int r = 0; r < 4; ++r) qp[m][r] = 0.f;
    #pragma unroll
    for (int n = 0; n < 2; ++n) {
        int gcol = cb * 256 + wv * 32 + n * 16 + l15;
        float b2v = b2[h * HID + gcol];
        float w3v = W3[h * HID + gcol];
        #pragma unroll
        for (int m = 0; m < 4; ++m)
            #pragma unroll
            for (int r = 0; r < 4; ++r)
                qp[m][r] += fmaxf(acc[m][n][r] + b2v, 0.f) * w3v;
    }
    #pragma unroll
    for (int m = 0; m < 4; ++m)
        #pragma unroll
        for (int r = 0; r < 4; ++r) {
            float v = qp[m][r];
            v += __shfl_xor(v, 1);
            v += __shfl_xor(v, 2);
            v += __shfl_xor(v, 4);
            v += __shfl_xor(v, 8);
            if (l15 == 0) red[wv][m * 16 + lk * 4 + r] = v;
        }
    __syncthreads();
    if (tid < 64) {
        float q = 0.f;
        #pragma unroll
        for (int s = 0; s < 8; ++s) q += red[s][tid];
        ws[WS_Q + (size_t)((cb * 2 + kh) * HEADS + h) * POP + rs * 64 + tid] = q;
    }
}

// The relu nonlinearity makes a K-split epilogue incorrect (see comment
// above). k_score_mfma12 below is the corrected kernel actually launched:
// identical structure, but kh splits COLUMNS (each block: 64 rows x 128
// cols x full K=16 chunks), so relu(acc+b2) stays exact per column and
// each of the 4 partials is a disjoint column-quarter sum.
__global__ __launch_bounds__(512, 4) void k_score_mfma12(
    const float* __restrict__ noise, const float* __restrict__ W1,
    const unsigned short* __restrict__ W2S,
    const float* __restrict__ b2, const float* __restrict__ W3,
    float* __restrict__ ws, int t)
{
    __shared__ unsigned short As[2][4096];
    __shared__ float red[8][64];

    const int tid = threadIdx.x;
    const int bid = blockIdx.x;
    // bijective XCD remap (2560 = 8*320); consecutive w share (h,cq) panel
    const int w = (bid & 7) * 320 + (bid >> 3);
    const int h = w >> 8;
    const int rem = w & 255;
    const int cq = rem >> 6;            // column-quarter 0..3 (128 cols)
    const int rs = rem & 63;            // row-stripe of 64

    const int lane = tid & 63;
    const int wv = tid >> 6;            // 0..7 -> 16-col strip
    const int l15 = lane & 15, lk = lane >> 4;

    // computeA role (all 512 threads, conflict-free pairing)
    const int akg = tid >> 7;
    const int arow = (tid >> 1) & 63;
    const int ahalf = tid & 1;

    const float* st = ws + WS_STATE;
    const float mu0 = st[0], mu1 = st[1], sd0 = st[2], sd1 = st[3];
    float2 e = *(const float2*)&noise[((size_t)t * POP + rs * 64 + arow) * 2];
    const float a0 = clip1(mu0 + sd0 * e.x);
    const float a1 = clip1(mu1 + sd1 * e.y);

    const float* base1 = ws + WS_BASE1 + h * HID;
    const float* w1u = W1 + ((size_t)h * 258 + 256) * HID;
    const float* w1v = W1 + ((size_t)h * 258 + 257) * HID;
    // column-quarter cq: cb = cq>>1 selects the 256-col slab; within-slab
    // column offset (cq&1)*128.
    const unsigned short* bslab = W2S + (size_t)((h * 2 + (cq >> 1)) * 16) * 16384;
    const int bco = lk * 2048 + ((cq & 1) * 128 + wv * 16 + l15) * 8;

    auto computeA = [&](int jc, int buf) {
        const int j = jc * 32 + akg * 8 + ahalf * 4;
        f32x4 b0 = *(const f32x4*)&base1[j];
        f32x4 u0 = *(const f32x4*)&w1u[j];
        f32x4 v0 = *(const f32x4*)&w1v[j];
        float hv[4];
        #pragma unroll
        for (int i = 0; i < 4; ++i)
            hv[i] = fmaxf(b0[i] + a0 * u0[i] + a1 * v0[i], 0.f);
        unsigned ph[2], pl[2];
        #pragma unroll
        for (int i = 0; i < 2; ++i) {
            ph[i] = pack2(hv[2 * i], hv[2 * i + 1]);
            float fx = __uint_as_float(ph[i] << 16);
            float fy = __uint_as_float(ph[i] & 0xFFFF0000u);
            pl[i] = pack2(hv[2 * i] - fx, hv[2 * i + 1] - fy);
        }
        uint2 HV, LV;
        HV.x = ph[0]; HV.y = ph[1];
        LV.x = pl[0]; LV.y = pl[1];
        const int ao = akg * 512 + arow * 8 + ahalf * 4;
        *(uint2*)&As[buf][ao] = HV;
        *(uint2*)&As[buf][2048 + ao] = LV;
    };

    f32x4 acc[4];      // 4 m-frags x 1 n-frag (16 cols/wave) = 16 AGPR
    f32x4 acc2[4];     // second accumulation chain over k-groups
    #pragma unroll
    for (int m = 0; m < 4; ++m) {
        acc[m] = (f32x4){0.f, 0.f, 0.f, 0.f};
        acc2[m] = (f32x4){0.f, 0.f, 0.f, 0.f};
    }

    computeA(0, 0);
    bf16x8 BH[2], BL[2];   // [kg-half] for the single 16-col n-frag
    #pragma unroll
    for (int g = 0; g < 2; ++g) {
        BH[g] = *(const bf16x8*)(bslab + g * 2048 * 0 + bco);   // kg=lk only
        BL[g] = *(const bf16x8*)(bslab + 8192 + bco);
    }
    // NOTE: with 16 cols/wave each wave needs only ONE B column-frag per
    // kg; lk already selects kg. BH[0]/BL[0] suffice; drop the second.
    __syncthreads();

    int cur = 0;
    #pragma unroll 1
    for (int kc = 0; kc < 16; ++kc) {
        bf16x8 AH[4], AL[4];
        #pragma unroll
        for (int m = 0; m < 4; ++m) {
            const int ad = lk * 512 + (m * 16 + l15) * 8;
            AH[m] = *(const bf16x8*)&As[cur][ad];
            AL[m] = *(const bf16x8*)&As[cur][2048 + ad];
        }
        const int nc = (kc < 15) ? kc + 1 : 15;
        const unsigned short* bnc = bslab + (size_t)nc * 16384;
        bf16x8 nBH, nBL;
        nBH = *(const bf16x8*)(bnc + bco);
        nBL = *(const bf16x8*)(bnc + 8192 + bco);
        const unsigned short* bcc = bslab + (size_t)kc * 16384;
        bf16x8 cBH = *(const bf16x8*)(bcc + bco);
        bf16x8 cBL = *(const bf16x8*)(bcc + 8192 + bco);
        __builtin_amdgcn_s_setprio(1);
        #pragma unroll
        for (int m = 0; m < 4; ++m)
            acc[m] = __builtin_amdgcn_mfma_f32_16x16x32_bf16(
                AH[m], cBH, acc[m], 0, 0, 0);
        #pragma unroll
        for (int m = 0; m < 4; ++m)
            acc2[m] = __builtin_amdgcn_mfma_f32_16x16x32_bf16(
                AL[m], cBH, acc2[m], 0, 0, 0);
        #pragma unroll
        for (int m = 0; m < 4; ++m)
            acc[m] = __builtin_amdgcn_mfma_f32_16x16x32_bf16(
                AH[m], cBL, acc[m], 0, 0, 0);
        __builtin_amdgcn_s_setprio(0);
        computeA(nc, cur ^ 1);
        __syncthreads();
        cur ^= 1;
        (void)nBH; (void)nBL;
    }

    const int gcol = cq * 128 + wv * 16 + l15;
    const float b2v = b2[h * HID + gcol];
    const float w3v = W3[h * HID + gcol];
    float qp[4][4];
    #pragma unroll
    for (int m = 0; m < 4; ++m)
        #pragma unroll
        for (int r = 0; r < 4; ++r)
            qp[m][r] = fmaxf(acc[m][r] + acc2[m][r] + b2v, 0.f) * w3v;
    #pragma unroll
    for (int m = 0; m < 4; ++m)
        #pragma unroll
        for (int r = 0; r < 4; ++r) {
            float v = qp[m][r];
            v += __shfl_xor(v, 1);
            v += __shfl_xor(v, 2);
            v += __shfl_xor(v, 4);
            v += __shfl_xor(v, 8);
            if (l15 == 0) red[wv][m * 16 + lk * 4 + r] = v;
        }
    __syncthreads();
    if (tid < 64) {
        float q = 0.f;
        #pragma unroll
        for (int s = 0; s < 8; ++s) q += red[s][tid];
        ws[WS_Q + (size_t)(cq * HEADS + h) * POP + rs * 64 + tid] = q;
    }
}

// ---------------------------------------------------------------------------
// Kernel 2 (fp32 fallback, used only if ws too small): writes part0, zeroes
// parts 1-3 so k_select's 4-partial sum stays correct.
// ---------------------------------------------------------------------------
__global__ __launch_bounds__(256) void k_score(const float* __restrict__ noise,
                                               const float* __restrict__ W1,
                                               const float* __restrict__ W2,
                                               const float* __restrict__ b2,
                                               const float* __restrict__ W3,
                                               float* __restrict__ ws, int t)
{
    __shared__ float h1[32][HID];
    __shared__ float a0s[32], a1s[32];
    __shared__ float red[2][16][2];

    const int tid = threadIdx.x;
    const int h   = blockIdx.y;
    const int p0  = blockIdx.x * 32;

    if (tid < 32) {
        const float* st = ws + WS_STATE;
        const int p = p0 + tid;
        float e0 = noise[((size_t)t * POP + p) * 2 + 0];
        float e1 = noise[((size_t)t * POP + p) * 2 + 1];
        a0s[tid] = fminf(fmaxf(st[0] + st[2] * e0, -1.f), 1.f);
        a1s[tid] = fminf(fmaxf(st[1] + st[3] * e1, -1.f), 1.f);
    }
    __syncthreads();

    const float* base1 = ws + WS_BASE1 + h * HID;
    const float* w1u = W1 + ((size_t)h * 258 + 256) * HID;
    const float* w1v = W1 + ((size_t)h * 258 + 257) * HID;
    #pragma unroll
    for (int jj = 0; jj < 2; ++jj) {
        int j = tid + jj * 256;
        float bb = base1[j], uu = w1u[j], vv = w1v[j];
        #pragma unroll
        for (int p = 0; p < 32; ++p)
            h1[p][j] = fmaxf(bb + a0s[p] * uu + a1s[p] * vv, 0.f);
    }
    __syncthreads();

    const int pg = tid >> 7;
    const int kl = tid & 127;
    const float* W2h = W2 + (size_t)h * HID * HID + kl;

    float acc[16][4];
    #pragma unroll
    for (int p = 0; p < 16; ++p)
        #pragma unroll
        for (int dk = 0; dk < 4; ++dk) acc[p][dk] = 0.f;

    for (int j0 = 0; j0 < HID; j0 += 4) {
        float w[4][4];
        #pragma unroll
        for (int dj = 0; dj < 4; ++dj)
            #pragma unroll
            for (int dk = 0; dk < 4; ++dk)
                w[dj][dk] = W2h[(size_t)(j0 + dj) * HID + dk * 128];
        #pragma unroll
        for (int p = 0; p < 16; ++p) {
            const float4 hv = *(const float4*)&h1[pg * 16 + p][j0];
            #pragma unroll
            for (int dk = 0; dk < 4; ++dk)
                acc[p][dk] += hv.x * w[0][dk] + hv.y * w[1][dk]
                            + hv.z * w[2][dk] + hv.w * w[3][dk];
        }
    }

    float b2v[4], w3v[4];
    #pragma unroll
    for (int dk = 0; dk < 4; ++dk) {
        b2v[dk] = b2[h * HID + kl + dk * 128];
        w3v[dk] = W3[h * HID + kl + dk * 128];
    }
    const int wid  = tid >> 6;
    const int lane = tid & 63;
    const int wig  = wid & 1;
    #pragma unroll
    for (int p = 0; p < 16; ++p) {
        float v = 0.f;
        #pragma unroll
        for (int dk = 0; dk < 4; ++dk)
            v += fmaxf(acc[p][dk] + b2v[dk], 0.f) * w3v[dk];
        #pragma unroll
        for (int off = 32; off; off >>= 1) v += __shfl_down(v, off);
        if (lane == 0) red[pg][p][wig] = v;
    }
    __syncthreads();
    if (tid < 32) {
        int pp = tid & 15, g = tid >> 4;
        ws[WS_Q + (size_t)h * POP + p0 + g * 16 + pp] =
            red[g][pp][0] + red[g][pp][1];
        ws[WS_Q + (size_t)(1 * HEADS + h) * POP + p0 + g * 16 + pp] = 0.f;
        ws[WS_Q + (size_t)(2 * HEADS + h) * POP + p0 + g * 16 + pp] = 0.f;
        ws[WS_Q + (size_t)(3 * HEADS + h) * POP + p0 + g * 16 + pp] = 0.f;
    }
}

// ---------------------------------------------------------------------------
// Kernel 3 (1024 threads): scores from 4 q partials (+b3), exact top-819
// radix select, elite mean/std (ddof=1, double accum), best_a update.
// ---------------------------------------------------------------------------
__global__ __launch_bounds__(1024) void k_select(const float* __restrict__ noise,
                                                 const float* __restrict__ b3,
                                                 float* __restrict__ ws,
                                                 float* __restrict__ out, int t)
{
    __shared__ float    sc[POP];
    __shared__ unsigned uk[POP];
    __shared__ unsigned hist[256];
    __shared__ int      scan2[1024];
    __shared__ float    rf[1024];
    __shared__ int      ri_[1024];
    __shared__ double   rd[1024];
    __shared__ unsigned s_prefix;
    __shared__ int      s_r;

    const int tid = threadIdx.x;
    const float* q = ws + WS_Q;
    float* st = ws + WS_STATE;
    const float mu0 = st[0], mu1 = st[1], sd0 = st[2], sd1 = st[3];

    // scores = mean_h min(q1,q2); q[h] = sum of 4 partials + b3[h]
    {
        const int p = tid * 4;
        f32x4 s = (f32x4){0.f, 0.f, 0.f, 0.f};
        #pragma unroll
        for (int hh = 0; hh < NH; ++hh) {
            f32x4 qa = (f32x4){0.f, 0.f, 0.f, 0.f};
            f32x4 qb = (f32x4){0.f, 0.f, 0.f, 0.f};
            #pragma unroll
            for (int pi = 0; pi < 4; ++pi) {
                f32x4 va = *(const f32x4*)&q[(size_t)(pi * HEADS + hh) * POP + p];
                f32x4 vb = *(const f32x4*)&q[(size_t)(pi * HEADS + NH + hh) * POP + p];
                #pragma unroll
                for (int i = 0; i < 4; ++i) { qa[i] += va[i]; qb[i] += vb[i]; }
            }
            float ba = b3[hh], bb = b3[NH + hh];
            #pragma unroll
            for (int i = 0; i < 4; ++i)
                s[i] += fminf(qa[i] + ba, qb[i] + bb);
        }
        #pragma unroll
        for (int i = 0; i < 4; ++i) {
            float v = s[i] * 0.2f;
            sc[p + i] = v;
            unsigned b = __float_as_uint(v);
            uk[p + i] = (b & 0x80000000u) ? ~b : (b | 0x80000000u);
        }
    }
    __syncthreads();

    // max + argmax (lowest index on ties)
    float mv = -3.402823466e38f; int mi = 0;
    #pragma unroll
    for (int k = 0; k < 4; ++k) {
        const int p = tid * 4 + k;
        float v = sc[p];
        if (v > mv) { mv = v; mi = p; }
    }
    rf[tid] = mv; ri_[tid] = mi;
    __syncthreads();
    for (int off = 512; off; off >>= 1) {
        if (tid < off) {
            float ov = rf[tid + off]; int oi = ri_[tid + off];
            if (ov > rf[tid] || (ov == rf[tid] && oi < ri_[tid])) {
                rf[tid] = ov; ri_[tid] = oi;
            }
        }
        __syncthreads();
    }
    const float maxsc = rf[0];
    const int argmax = ri_[0];
    __syncthreads();

    // radix select with parallel suffix-scan digit pick
    unsigned prefix = 0; int r = ELITE;
    for (int shift = 24; shift >= 0; shift -= 8) {
        if (tid < 256) hist[tid] = 0;
        __syncthreads();
        const unsigned himask = (shift < 24) ? (0xFFFFFFFFu << (shift + 8)) : 0u;
        for (int p = tid; p < POP; p += 1024) {
            unsigned key = uk[p];
            if ((key & himask) == prefix)
                atomicAdd(&hist[(key >> shift) & 255u], 1u);
        }
        __syncthreads();
        scan2[tid] = (tid < 256) ? (int)hist[tid] : 0;
        __syncthreads();
        for (int off = 1; off < 256; off <<= 1) {
            int v = (tid < 256 && tid + off < 256) ? scan2[tid + off] : 0;
            __syncthreads();
            if (tid < 256) scan2[tid] += v;
            __syncthreads();
        }
        if (tid < 256) {
            int above = (tid < 255) ? scan2[tid + 1] : 0;
            if (scan2[tid] >= r && above < r) {
                s_prefix = prefix | ((unsigned)tid << shift);
                s_r = r - above;
            }
        }
        __syncthreads();
        prefix = s_prefix; r = s_r;
        __syncthreads();
    }
    const unsigned uT = prefix;
    const int take = r;

    // tie ranks (index order) via prefix scan over contiguous 4-chunks
    int tieloc = 0;
    {
        const int base = tid * 4;
        #pragma unroll
        for (int k = 0; k < 4; ++k) if (uk[base + k] == uT) tieloc++;
    }
    scan2[tid] = tieloc;
    __syncthreads();
    for (int off = 1; off < 1024; off <<= 1) {
        int v = (tid >= off) ? scan2[tid - off] : 0;
        __syncthreads();
        scan2[tid] += v;
        __syncthreads();
    }
    const int tieExcl = scan2[tid] - tieloc;

    double s0 = 0, s1 = 0, ss0 = 0, ss1 = 0;
    {
        const int base = tid * 4;
        int trank = tieExcl;
        #pragma unroll
        for (int k = 0; k < 4; ++k) {
            const int p = base + k;
            const unsigned key = uk[p];
            bool inc = false;
            if (key > uT) inc = true;
            else if (key == uT) { if (trank < take) inc = true; trank++; }
            if (inc) {
                float e0 = noise[((size_t)t * POP + p) * 2 + 0];
                float e1 = noise[((size_t)t * POP + p) * 2 + 1];
                float a0 = fminf(fmaxf(mu0 + sd0 * e0, -1.f), 1.f);
                float a1 = fminf(fmaxf(mu1 + sd1 * e1, -1.f), 1.f);
                s0 += a0; s1 += a1;
                ss0 += (double)a0 * a0; ss1 += (double)a1 * a1;
            }
        }
    }
    double S0, S1, SS0, SS1;
    rd[tid] = s0;  __syncthreads();
    for (int off = 512; off; off >>= 1) { if (tid < off) rd[tid] += rd[tid + off]; __syncthreads(); }
    S0 = rd[0]; __syncthreads();
    rd[tid] = s1;  __syncthreads();
    for (int off = 512; off; off >>= 1) { if (tid < off) rd[tid] += rd[tid + off]; __syncthreads(); }
    S1 = rd[0]; __syncthreads();
    rd[tid] = ss0; __syncthreads();
    for (int off = 512; off; off >>= 1) { if (tid < off) rd[tid] += rd[tid + off]; __syncthreads(); }
    SS0 = rd[0]; __syncthreads();
    rd[tid] = ss1; __syncthreads();
    for (int off = 512; off; off >>= 1) { if (tid < off) rd[tid] += rd[tid + off]; __syncthreads(); }
    SS1 = rd[0]; __syncthreads();

    if (tid == 0) {
        const double n = (double)ELITE;
        double m0 = S0 / n, m1 = S1 / n;
        double v0 = (SS0 - S0 * S0 / n) / (n - 1.0);
        double v1 = (SS1 - S1 * S1 / n) / (n - 1.0);
        float nsd0 = fmaxf((float)sqrt(fmax(v0, 0.0)), MIN_STDF);
        float nsd1 = fmaxf((float)sqrt(fmax(v1, 0.0)), MIN_STDF);
        float e0 = noise[((size_t)t * POP + argmax) * 2 + 0];
        float e1 = noise[((size_t)t * POP + argmax) * 2 + 1];
        float a0 = fminf(fmaxf(mu0 + sd0 * e0, -1.f), 1.f);
        float a1 = fminf(fmaxf(mu1 + sd1 * e1, -1.f), 1.f);
        if (maxsc > st[6]) { st[4] = a0; st[5] = a1; st[6] = maxsc; }
        st[0] = (float)m0; st[1] = (float)m1; st[2] = nsd0; st[3] = nsd1;
        if (t == ITERS - 1) { out[0] = st[4]; out[1] = st[5]; }
    }
}

// ---------------------------------------------------------------------------
extern "C" void kernel_launch(void* const* d_in, const int* in_sizes, int n_in,
                              void* d_out, int out_size, void* d_ws, size_t ws_size,
                              hipStream_t stream)
{
    const float* state = (const float*)d_in[0];
    const float* noise = (const float*)d_in[1];
    const float* W1    = (const float*)d_in[2];
    const float* b1    = (const float*)d_in[3];
    const float* W2    = (const float*)d_in[4];
    const float* b2    = (const float*)d_in[5];
    const float* W3    = (const float*)d_in[6];
    const float* b3    = (const float*)d_in[7];
    float* out = (float*)d_out;
    float* ws  = (float*)d_ws;

    const bool fast = ws_size >= WS_NEED_BYTES;

    k_base<<<dim3(2, HEADS), 256, 0, stream>>>(state, W1, b1, ws);
    if (fast) {
        unsigned short* W2S = (unsigned short*)((char*)d_ws + WS_W2S_BYTE);
        k_split<<<dim3(16, 2, HEADS), 256, 0, stream>>>(W2, W2S);
        for (int t = 0; t < ITERS; ++t) {
            k_score_mfma12<<<dim3(2560), 512, 0, stream>>>(
                noise, W1, W2S, b2, W3, ws, t);
            k_select<<<1, 1024, 0, stream>>>(noise, b3, ws, out, t);
        }
    } else {
        for (int t = 0; t < ITERS; ++t) {
            k_score<<<dim3(POP / 32, HEADS), 256, 0, stream>>>(noise, W1, W2, b2, W3, ws, t);
            k_select<<<1, 1024, 0, stream>>>(noise, b3, ws, out, t);
        }
    }
}

// Round 14
// 317.957 us; speedup vs baseline: 1.3643x; 1.3643x over previous
//
#include <hip/hip_runtime.h>
#include <math.h>

#define SDIM   256
#define HID    512
#define NH     5
#define HEADS  10
#define POP    4096
#define ITERS  4
#define ELITE  819
#define INIT_STDF 0.4f
#define MIN_STDF  0.1f

// ws layout (R12 champion layout):
//   floats: base1[10][512] @0, q_part[2][10][4096] @5120, state @87040 (7 f)
//   bytes WS_W2S_BYTE+: W2S split/transposed weights, slab layout:
//   [h][cb(2)][jc(16)] slabs of 16384 ushorts: {hi[kg4][col256][ji8], lo[...]}
#define WS_BASE1 0
#define WS_Q     5120
#define WS_STATE 87040
#define WS_W2S_BYTE 348224
#define W2S_USHORTS (HEADS * 2 * 16 * 16384)
#define WS_NEED_BYTES (WS_W2S_BYTE + (size_t)W2S_USHORTS * 2)

typedef __attribute__((ext_vector_type(4))) float f32x4;
typedef __attribute__((ext_vector_type(8))) short bf16x8;

static __device__ __forceinline__ unsigned short bf16_rne(float x) {
    unsigned b = __float_as_uint(x);
    return (unsigned short)((b + 0x7FFFu + ((b >> 16) & 1u)) >> 16);
}

// packed f32x2 -> bf16x2 (hardware cvt_pk, RNE)
static __device__ __forceinline__ unsigned pack2(float x, float y) {
    unsigned r;
    asm("v_cvt_pk_bf16_f32 %0, %1, %2" : "=v"(r) : "v"(x), "v"(y));
    return r;
}

static __device__ __forceinline__ float clip1(float x) {
    return fminf(fmaxf(x, -1.f), 1.f);
}

// ---------------------------------------------------------------------------
// Kernel 1: base1[h][j] = b1[h][j] + sum_i s[i] * W1[h][i][j]; init state
// ---------------------------------------------------------------------------
__global__ __launch_bounds__(256) void k_base(const float* __restrict__ state,
                                              const float* __restrict__ W1,
                                              const float* __restrict__ b1,
                                              float* __restrict__ ws)
{
    const int h = blockIdx.y;
    const int j = blockIdx.x * 256 + threadIdx.x;
    const float* w1h = W1 + (size_t)h * 258 * HID;
    float acc = b1[h * HID + j];
    for (int i = 0; i < SDIM; ++i)
        acc += state[i] * w1h[(size_t)i * HID + j];
    ws[WS_BASE1 + h * HID + j] = acc;

    if (h == 0 && blockIdx.x == 0 && threadIdx.x == 0) {
        float* st = ws + WS_STATE;
        st[0] = 0.f; st[1] = 0.f;
        st[2] = INIT_STDF; st[3] = INIT_STDF;
        st[4] = 0.f; st[5] = 0.f;
        st[6] = -3.402823466e38f;
    }
}

// ---------------------------------------------------------------------------
// Kernel 1b: W2 -> W2S (transpose + RNE hi/lo split). Coalesced both sides.
// ---------------------------------------------------------------------------
__global__ __launch_bounds__(256) void k_split(const float* __restrict__ W2,
                                               unsigned short* __restrict__ W2S)
{
    const int h = blockIdx.z, cb = blockIdx.y, jc = blockIdx.x;
    const int c = threadIdx.x;
    unsigned short* slab = W2S + (size_t)((h * 2 + cb) * 16 + jc) * 16384;
    #pragma unroll
    for (int jg = 0; jg < 4; ++jg) {
        unsigned hp[4], lp[4];
        #pragma unroll
        for (int i = 0; i < 4; ++i) {
            const int j = jc * 32 + jg * 8 + 2 * i;
            float v0 = W2[(size_t)(h * HID + j) * HID + cb * 256 + c];
            float v1 = W2[(size_t)(h * HID + j + 1) * HID + cb * 256 + c];
            unsigned short h0 = bf16_rne(v0), h1 = bf16_rne(v1);
            float f0 = __uint_as_float((unsigned)h0 << 16);
            float f1 = __uint_as_float((unsigned)h1 << 16);
            unsigned short l0 = bf16_rne(v0 - f0), l1 = bf16_rne(v1 - f1);
            hp[i] = (unsigned)h0 | ((unsigned)h1 << 16);
            lp[i] = (unsigned)l0 | ((unsigned)l1 << 16);
        }
        uint4 HV, LV;
        HV.x = hp[0]; HV.y = hp[1]; HV.z = hp[2]; HV.w = hp[3];
        LV.x = lp[0]; LV.y = lp[1]; LV.z = lp[2]; LV.w = lp[3];
        *(uint4*)&slab[jg * 2048 + c * 8] = HV;
        *(uint4*)&slab[8192 + jg * 2048 + c * 8] = LV;
    }
}

// ---------------------------------------------------------------------------
// Kernel 2 (champion structure + BK=64): 512 thr / 8 waves = 64 rows x 256
// cols (cb half of HID), full K; grid 1280. Wave = 64 rows x 32 cols,
// acc[4][2] = 32 AGPR (unified ~108 <= 128 -> 4 waves/SIMD). TWO 32-k
// chunks per barrier (8 barriers, was 16): longer phases let resident
// waves drift so LDS/VALU/MFMA pipes mix instead of marching in lockstep.
// A: 64-k tile computed into LDS dbuf (2x16KB) by all 512 threads with
// the R13 conflict-free pairing. B: direct global->VGPR, two register
// sets (Bc/Bn) alternating, always one chunk ahead.
// Writes q_part[cb][h][row]; k_select sums the 2 partials.
// ---------------------------------------------------------------------------
__global__ __launch_bounds__(512, 4) void k_score_mfma13(
    const float* __restrict__ noise, const float* __restrict__ W1,
    const unsigned short* __restrict__ W2S,
    const float* __restrict__ b2, const float* __restrict__ W3,
    float* __restrict__ ws, int t)
{
    __shared__ unsigned short As[2][8192];   // dbuf of 64k tiles:
    // half s at s*4096: {hi[kg4][row64][ji8] @0, lo @+2048}
    __shared__ float red[8][64];

    const int tid = threadIdx.x;
    const int bid = blockIdx.x;
    // bijective XCD remap (1280 = 8*160): consecutive w share (h,cb) panel
    const int w = (bid & 7) * 160 + (bid >> 3);
    const int h = w >> 7;
    const int rem = w & 127;
    const int cb = rem >> 6;
    const int rs = rem & 63;            // row-stripe of 64

    const int lane = tid & 63;
    const int wv = tid >> 6;            // 0..7 -> 32-col strip
    const int l15 = lane & 15, lk = lane >> 4;

    // computeA role (all 512 threads, conflict-free pairing, 8 elem each):
    // akg = tid>>7 (0..3), row = (tid>>1)&63, half4 = tid&1; covers both
    // 32-k halves (s=0,1) of the 64-k tile.
    const int akg = tid >> 7;
    const int arow = (tid >> 1) & 63;
    const int ahalf = tid & 1;

    const float* st = ws + WS_STATE;
    const float mu0 = st[0], mu1 = st[1], sd0 = st[2], sd1 = st[3];
    float2 e = *(const float2*)&noise[((size_t)t * POP + rs * 64 + arow) * 2];
    const float a0 = clip1(mu0 + sd0 * e.x);
    const float a1 = clip1(mu1 + sd1 * e.y);

    const float* base1 = ws + WS_BASE1 + h * HID;
    const float* w1u = W1 + ((size_t)h * 258 + 256) * HID;
    const float* w1v = W1 + ((size_t)h * 258 + 257) * HID;
    const unsigned short* bslab = W2S + (size_t)((h * 2 + cb) * 16) * 16384;
    // B frag: kg=lk, col = wv*32 + n*16 + l15 (lo at +8192)
    const int bco = lk * 2048 + (wv * 32 + l15) * 8;

    // compute A 64-k tile `it8` (rank-2 + relu + cvt_pk split) into As[buf]
    auto computeA = [&](int it8, int buf) {
        #pragma unroll
        for (int s = 0; s < 2; ++s) {
            const int j = it8 * 64 + s * 32 + akg * 8 + ahalf * 4;
            f32x4 b0 = *(const f32x4*)&base1[j];
            f32x4 u0 = *(const f32x4*)&w1u[j];
            f32x4 v0 = *(const f32x4*)&w1v[j];
            float hv[4];
            #pragma unroll
            for (int i = 0; i < 4; ++i)
                hv[i] = fmaxf(b0[i] + a0 * u0[i] + a1 * v0[i], 0.f);
            unsigned ph[2], pl[2];
            #pragma unroll
            for (int i = 0; i < 2; ++i) {
                ph[i] = pack2(hv[2 * i], hv[2 * i + 1]);
                float fx = __uint_as_float(ph[i] << 16);
                float fy = __uint_as_float(ph[i] & 0xFFFF0000u);
                pl[i] = pack2(hv[2 * i] - fx, hv[2 * i + 1] - fy);
            }
            uint2 HV, LV;
            HV.x = ph[0]; HV.y = ph[1];
            LV.x = pl[0]; LV.y = pl[1];
            const int ao = s * 4096 + akg * 512 + arow * 8 + ahalf * 4;
            *(uint2*)&As[buf][ao] = HV;
            *(uint2*)&As[buf][2048 + ao] = LV;
        }
    };

    f32x4 acc[4][2];
    #pragma unroll
    for (int m = 0; m < 4; ++m)
        #pragma unroll
        for (int n = 0; n < 2; ++n)
            acc[m][n] = (f32x4){0.f, 0.f, 0.f, 0.f};

    // prologue: A tile 0 into buf 0; B chunk 0 into Bc
    computeA(0, 0);
    bf16x8 BcH[2], BcL[2], BnH[2], BnL[2];
    #pragma unroll
    for (int n = 0; n < 2; ++n) {
        BcH[n] = *(const bf16x8*)(bslab + bco + n * 128);
        BcL[n] = *(const bf16x8*)(bslab + 8192 + bco + n * 128);
    }
    __syncthreads();

    int cur = 0;
    #pragma unroll 1
    for (int it = 0; it < 8; ++it) {
        // ---------- sub 0: chunk 2it (A half 0, B = Bc) ----------
        bf16x8 AH[4], AL[4];
        #pragma unroll
        for (int m = 0; m < 4; ++m) {
            const int ad = lk * 512 + (m * 16 + l15) * 8;
            AH[m] = *(const bf16x8*)&As[cur][ad];
            AL[m] = *(const bf16x8*)&As[cur][2048 + ad];
        }
        // prefetch B chunk 2it+1 into Bn (hidden under sub0 MFMAs)
        {
            const unsigned short* bp = bslab + (size_t)(it * 2 + 1) * 16384;
            #pragma unroll
            for (int n = 0; n < 2; ++n) {
                BnH[n] = *(const bf16x8*)(bp + bco + n * 128);
                BnL[n] = *(const bf16x8*)(bp + 8192 + bco + n * 128);
            }
        }
        __builtin_amdgcn_s_setprio(1);
        #pragma unroll
        for (int m = 0; m < 4; ++m)
            #pragma unroll
            for (int n = 0; n < 2; ++n)
                acc[m][n] = __builtin_amdgcn_mfma_f32_16x16x32_bf16(
                    AH[m], BcH[n], acc[m][n], 0, 0, 0);
        #pragma unroll
        for (int m = 0; m < 4; ++m)
            #pragma unroll
            for (int n = 0; n < 2; ++n)
                acc[m][n] = __builtin_amdgcn_mfma_f32_16x16x32_bf16(
                    AL[m], BcH[n], acc[m][n], 0, 0, 0);
        #pragma unroll
        for (int m = 0; m < 4; ++m)
            #pragma unroll
            for (int n = 0; n < 2; ++n)
                acc[m][n] = __builtin_amdgcn_mfma_f32_16x16x32_bf16(
                    AH[m], BcL[n], acc[m][n], 0, 0, 0);
        __builtin_amdgcn_s_setprio(0);

        // ---------- sub 1: chunk 2it+1 (A half 1, B = Bn) ----------
        #pragma unroll
        for (int m = 0; m < 4; ++m) {
            const int ad = 4096 + lk * 512 + (m * 16 + l15) * 8;
            AH[m] = *(const bf16x8*)&As[cur][ad];
            AL[m] = *(const bf16x8*)&As[cur][2048 + ad];
        }
        // prefetch B chunk 2it+2 (clamped) into Bc (WAR-safe: issued after
        // sub0 MFMAs consumed Bc in program order)
        {
            const int nc = (it < 7) ? it * 2 + 2 : 15;
            const unsigned short* bp = bslab + (size_t)nc * 16384;
            #pragma unroll
            for (int n = 0; n < 2; ++n) {
                BcH[n] = *(const bf16x8*)(bp + bco + n * 128);
                BcL[n] = *(const bf16x8*)(bp + 8192 + bco + n * 128);
            }
        }
        __builtin_amdgcn_s_setprio(1);
        #pragma unroll
        for (int m = 0; m < 4; ++m)
            #pragma unroll
            for (int n = 0; n < 2; ++n)
                acc[m][n] = __builtin_amdgcn_mfma_f32_16x16x32_bf16(
                    AH[m], BnH[n], acc[m][n], 0, 0, 0);
        #pragma unroll
        for (int m = 0; m < 4; ++m)
            #pragma unroll
            for (int n = 0; n < 2; ++n)
                acc[m][n] = __builtin_amdgcn_mfma_f32_16x16x32_bf16(
                    AL[m], BnH[n], acc[m][n], 0, 0, 0);
        #pragma unroll
        for (int m = 0; m < 4; ++m)
            #pragma unroll
            for (int n = 0; n < 2; ++n)
                acc[m][n] = __builtin_amdgcn_mfma_f32_16x16x32_bf16(
                    AH[m], BnL[n], acc[m][n], 0, 0, 0);
        __builtin_amdgcn_s_setprio(0);

        // next 64-k A tile, then the single barrier of this iteration
        computeA((it < 7) ? it + 1 : 7, cur ^ 1);
        __syncthreads();
        cur ^= 1;
    }

    // epilogue: q_part = sum over this block's 256 cols of
    //           relu(acc + b2[col]) * W3[col]
    // C layout (m89): col = l15, row = lk*4 + reg (+16 per m-frag)
    float qp[4][4];
    #pragma unroll
    for (int m = 0; m < 4; ++m)
        #pragma unroll
        for (int r = 0; r < 4; ++r) qp[m][r] = 0.f;
    #pragma unroll
    for (int n = 0; n < 2; ++n) {
        int gcol = cb * 256 + wv * 32 + n * 16 + l15;
        float b2v = b2[h * HID + gcol];
        float w3v = W3[h * HID + gcol];
        #pragma unroll
        for (int m = 0; m < 4; ++m)
            #pragma unroll
            for (int r = 0; r < 4; ++r)
                qp[m][r] += fmaxf(acc[m][n][r] + b2v, 0.f) * w3v;
    }
    #pragma unroll
    for (int m = 0; m < 4; ++m)
        #pragma unroll
        for (int r = 0; r < 4; ++r) {
            float v = qp[m][r];
            v += __shfl_xor(v, 1);
            v += __shfl_xor(v, 2);
            v += __shfl_xor(v, 4);
            v += __shfl_xor(v, 8);
            if (l15 == 0) red[wv][m * 16 + lk * 4 + r] = v;
        }
    __syncthreads();
    if (tid < 64) {
        float q = 0.f;
        #pragma unroll
        for (int s = 0; s < 8; ++s) q += red[s][tid];
        ws[WS_Q + (size_t)(cb * HEADS + h) * POP + rs * 64 + tid] = q;
    }
}

// ---------------------------------------------------------------------------
// Kernel 2 (fp32 fallback, used only if ws too small): writes part0, zeroes
// part1 so k_select's partial-sum read stays correct.
// ---------------------------------------------------------------------------
__global__ __launch_bounds__(256) void k_score(const float* __restrict__ noise,
                                               const float* __restrict__ W1,
                                               const float* __restrict__ W2,
                                               const float* __restrict__ b2,
                                               const float* __restrict__ W3,
                                               float* __restrict__ ws, int t)
{
    __shared__ float h1[32][HID];
    __shared__ float a0s[32], a1s[32];
    __shared__ float red[2][16][2];

    const int tid = threadIdx.x;
    const int h   = blockIdx.y;
    const int p0  = blockIdx.x * 32;

    if (tid < 32) {
        const float* st = ws + WS_STATE;
        const int p = p0 + tid;
        float e0 = noise[((size_t)t * POP + p) * 2 + 0];
        float e1 = noise[((size_t)t * POP + p) * 2 + 1];
        a0s[tid] = fminf(fmaxf(st[0] + st[2] * e0, -1.f), 1.f);
        a1s[tid] = fminf(fmaxf(st[1] + st[3] * e1, -1.f), 1.f);
    }
    __syncthreads();

    const float* base1 = ws + WS_BASE1 + h * HID;
    const float* w1u = W1 + ((size_t)h * 258 + 256) * HID;
    const float* w1v = W1 + ((size_t)h * 258 + 257) * HID;
    #pragma unroll
    for (int jj = 0; jj < 2; ++jj) {
        int j = tid + jj * 256;
        float bb = base1[j], uu = w1u[j], vv = w1v[j];
        #pragma unroll
        for (int p = 0; p < 32; ++p)
            h1[p][j] = fmaxf(bb + a0s[p] * uu + a1s[p] * vv, 0.f);
    }
    __syncthreads();

    const int pg = tid >> 7;
    const int kl = tid & 127;
    const float* W2h = W2 + (size_t)h * HID * HID + kl;

    float acc[16][4];
    #pragma unroll
    for (int p = 0; p < 16; ++p)
        #pragma unroll
        for (int dk = 0; dk < 4; ++dk) acc[p][dk] = 0.f;

    for (int j0 = 0; j0 < HID; j0 += 4) {
        float w[4][4];
        #pragma unroll
        for (int dj = 0; dj < 4; ++dj)
            #pragma unroll
            for (int dk = 0; dk < 4; ++dk)
                w[dj][dk] = W2h[(size_t)(j0 + dj) * HID + dk * 128];
        #pragma unroll
        for (int p = 0; p < 16; ++p) {
            const float4 hv = *(const float4*)&h1[pg * 16 + p][j0];
            #pragma unroll
            for (int dk = 0; dk < 4; ++dk)
                acc[p][dk] += hv.x * w[0][dk] + hv.y * w[1][dk]
                            + hv.z * w[2][dk] + hv.w * w[3][dk];
        }
    }

    float b2v[4], w3v[4];
    #pragma unroll
    for (int dk = 0; dk < 4; ++dk) {
        b2v[dk] = b2[h * HID + kl + dk * 128];
        w3v[dk] = W3[h * HID + kl + dk * 128];
    }
    const int wid  = tid >> 6;
    const int lane = tid & 63;
    const int wig  = wid & 1;
    #pragma unroll
    for (int p = 0; p < 16; ++p) {
        float v = 0.f;
        #pragma unroll
        for (int dk = 0; dk < 4; ++dk)
            v += fmaxf(acc[p][dk] + b2v[dk], 0.f) * w3v[dk];
        #pragma unroll
        for (int off = 32; off; off >>= 1) v += __shfl_down(v, off);
        if (lane == 0) red[pg][p][wig] = v;
    }
    __syncthreads();
    if (tid < 32) {
        int pp = tid & 15, g = tid >> 4;
        ws[WS_Q + (size_t)h * POP + p0 + g * 16 + pp] =
            red[g][pp][0] + red[g][pp][1];
        ws[WS_Q + (size_t)(HEADS + h) * POP + p0 + g * 16 + pp] = 0.f;
    }
}

// ---------------------------------------------------------------------------
// Kernel 3 (1024 threads): scores from 2 q partials (+b3), exact top-819
// radix select, elite mean/std (ddof=1, double accum), best_a update.
// ---------------------------------------------------------------------------
__global__ __launch_bounds__(1024) void k_select(const float* __restrict__ noise,
                                                 const float* __restrict__ b3,
                                                 float* __restrict__ ws,
                                                 float* __restrict__ out, int t)
{
    __shared__ float    sc[POP];
    __shared__ unsigned uk[POP];
    __shared__ unsigned hist[256];
    __shared__ int      scan2[1024];
    __shared__ float    rf[1024];
    __shared__ int      ri_[1024];
    __shared__ double   rd[1024];
    __shared__ unsigned s_prefix;
    __shared__ int      s_r;

    const int tid = threadIdx.x;
    const float* q = ws + WS_Q;
    float* st = ws + WS_STATE;
    const float mu0 = st[0], mu1 = st[1], sd0 = st[2], sd1 = st[3];

    // scores = mean_h min(q1,q2); q[h] = part0 + part1 + b3[h]
    {
        const int p = tid * 4;
        f32x4 s = (f32x4){0.f, 0.f, 0.f, 0.f};
        #pragma unroll
        for (int hh = 0; hh < NH; ++hh) {
            f32x4 qa0 = *(const f32x4*)&q[(size_t)hh * POP + p];
            f32x4 qa1 = *(const f32x4*)&q[(size_t)(HEADS + hh) * POP + p];
            f32x4 qb0 = *(const f32x4*)&q[(size_t)(NH + hh) * POP + p];
            f32x4 qb1 = *(const f32x4*)&q[(size_t)(HEADS + NH + hh) * POP + p];
            float ba = b3[hh], bb = b3[NH + hh];
            #pragma unroll
            for (int i = 0; i < 4; ++i)
                s[i] += fminf(qa0[i] + qa1[i] + ba, qb0[i] + qb1[i] + bb);
        }
        #pragma unroll
        for (int i = 0; i < 4; ++i) {
            float v = s[i] * 0.2f;
            sc[p + i] = v;
            unsigned b = __float_as_uint(v);
            uk[p + i] = (b & 0x80000000u) ? ~b : (b | 0x80000000u);
        }
    }
    __syncthreads();

    // max + argmax (lowest index on ties)
    float mv = -3.402823466e38f; int mi = 0;
    #pragma unroll
    for (int k = 0; k < 4; ++k) {
        const int p = tid * 4 + k;
        float v = sc[p];
        if (v > mv) { mv = v; mi = p; }
    }
    rf[tid] = mv; ri_[tid] = mi;
    __syncthreads();
    for (int off = 512; off; off >>= 1) {
        if (tid < off) {
            float ov = rf[tid + off]; int oi = ri_[tid + off];
            if (ov > rf[tid] || (ov == rf[tid] && oi < ri_[tid])) {
                rf[tid] = ov; ri_[tid] = oi;
            }
        }
        __syncthreads();
    }
    const float maxsc = rf[0];
    const int argmax = ri_[0];
    __syncthreads();

    // radix select with parallel suffix-scan digit pick
    unsigned prefix = 0; int r = ELITE;
    for (int shift = 24; shift >= 0; shift -= 8) {
        if (tid < 256) hist[tid] = 0;
        __syncthreads();
        const unsigned himask = (shift < 24) ? (0xFFFFFFFFu << (shift + 8)) : 0u;
        for (int p = tid; p < POP; p += 1024) {
            unsigned key = uk[p];
            if ((key & himask) == prefix)
                atomicAdd(&hist[(key >> shift) & 255u], 1u);
        }
        __syncthreads();
        scan2[tid] = (tid < 256) ? (int)hist[tid] : 0;
        __syncthreads();
        for (int off = 1; off < 256; off <<= 1) {
            int v = (tid < 256 && tid + off < 256) ? scan2[tid + off] : 0;
            __syncthreads();
            if (tid < 256) scan2[tid] += v;
            __syncthreads();
        }
        if (tid < 256) {
            int above = (tid < 255) ? scan2[tid + 1] : 0;
            if (scan2[tid] >= r && above < r) {
                s_prefix = prefix | ((unsigned)tid << shift);
                s_r = r - above;
            }
        }
        __syncthreads();
        prefix = s_prefix; r = s_r;
        __syncthreads();
    }
    const unsigned uT = prefix;
    const int take = r;

    // tie ranks (index order) via prefix scan over contiguous 4-chunks
    int tieloc = 0;
    {
        const int base = tid * 4;
        #pragma unroll
        for (int k = 0; k < 4; ++k) if (uk[base + k] == uT) tieloc++;
    }
    scan2[tid] = tieloc;
    __syncthreads();
    for (int off = 1; off < 1024; off <<= 1) {
        int v = (tid >= off) ? scan2[tid - off] : 0;
        __syncthreads();
        scan2[tid] += v;
        __syncthreads();
    }
    const int tieExcl = scan2[tid] - tieloc;

    double s0 = 0, s1 = 0, ss0 = 0, ss1 = 0;
    {
        const int base = tid * 4;
        int trank = tieExcl;
        #pragma unroll
        for (int k = 0; k < 4; ++k) {
            const int p = base + k;
            const unsigned key = uk[p];
            bool inc = false;
            if (key > uT) inc = true;
            else if (key == uT) { if (trank < take) inc = true; trank++; }
            if (inc) {
                float e0 = noise[((size_t)t * POP + p) * 2 + 0];
                float e1 = noise[((size_t)t * POP + p) * 2 + 1];
                float a0 = fminf(fmaxf(mu0 + sd0 * e0, -1.f), 1.f);
                float a1 = fminf(fmaxf(mu1 + sd1 * e1, -1.f), 1.f);
                s0 += a0; s1 += a1;
                ss0 += (double)a0 * a0; ss1 += (double)a1 * a1;
            }
        }
    }
    double S0, S1, SS0, SS1;
    rd[tid] = s0;  __syncthreads();
    for (int off = 512; off; off >>= 1) { if (tid < off) rd[tid] += rd[tid + off]; __syncthreads(); }
    S0 = rd[0]; __syncthreads();
    rd[tid] = s1;  __syncthreads();
    for (int off = 512; off; off >>= 1) { if (tid < off) rd[tid] += rd[tid + off]; __syncthreads(); }
    S1 = rd[0]; __syncthreads();
    rd[tid] = ss0; __syncthreads();
    for (int off = 512; off; off >>= 1) { if (tid < off) rd[tid] += rd[tid + off]; __syncthreads(); }
    SS0 = rd[0]; __syncthreads();
    rd[tid] = ss1; __syncthreads();
    for (int off = 512; off; off >>= 1) { if (tid < off) rd[tid] += rd[tid + off]; __syncthreads(); }
    SS1 = rd[0]; __syncthreads();

    if (tid == 0) {
        const double n = (double)ELITE;
        double m0 = S0 / n, m1 = S1 / n;
        double v0 = (SS0 - S0 * S0 / n) / (n - 1.0);
        double v1 = (SS1 - S1 * S1 / n) / (n - 1.0);
        float nsd0 = fmaxf((float)sqrt(fmax(v0, 0.0)), MIN_STDF);
        float nsd1 = fmaxf((float)sqrt(fmax(v1, 0.0)), MIN_STDF);
        float e0 = noise[((size_t)t * POP + argmax) * 2 + 0];
        float e1 = noise[((size_t)t * POP + argmax) * 2 + 1];
        float a0 = fminf(fmaxf(mu0 + sd0 * e0, -1.f), 1.f);
        float a1 = fminf(fmaxf(mu1 + sd1 * e1, -1.f), 1.f);
        if (maxsc > st[6]) { st[4] = a0; st[5] = a1; st[6] = maxsc; }
        st[0] = (float)m0; st[1] = (float)m1; st[2] = nsd0; st[3] = nsd1;
        if (t == ITERS - 1) { out[0] = st[4]; out[1] = st[5]; }
    }
}

// ---------------------------------------------------------------------------
extern "C" void kernel_launch(void* const* d_in, const int* in_sizes, int n_in,
                              void* d_out, int out_size, void* d_ws, size_t ws_size,
                              hipStream_t stream)
{
    const float* state = (const float*)d_in[0];
    const float* noise = (const float*)d_in[1];
    const float* W1    = (const float*)d_in[2];
    const float* b1    = (const float*)d_in[3];
    const float* W2    = (const float*)d_in[4];
    const float* b2    = (const float*)d_in[5];
    const float* W3    = (const float*)d_in[6];
    const float* b3    = (const float*)d_in[7];
    float* out = (float*)d_out;
    float* ws  = (float*)d_ws;

    const bool fast = ws_size >= WS_NEED_BYTES;

    k_base<<<dim3(2, HEADS), 256, 0, stream>>>(state, W1, b1, ws);
    if (fast) {
        unsigned short* W2S = (unsigned short*)((char*)d_ws + WS_W2S_BYTE);
        k_split<<<dim3(16, 2, HEADS), 256, 0, stream>>>(W2, W2S);
        for (int t = 0; t < ITERS; ++t) {
            k_score_mfma13<<<dim3(1280), 512, 0, stream>>>(
                noise, W1, W2S, b2, W3, ws, t);
            k_select<<<1, 1024, 0, stream>>>(noise, b3, ws, out, t);
        }
    } else {
        for (int t = 0; t < ITERS; ++t) {
            k_score<<<dim3(POP / 32, HEADS), 256, 0, stream>>>(noise, W1, W2, b2, W3, ws, t);
            k_select<<<1, 1024, 0, stream>>>(noise, b3, ws, out, t);
        }
    }
}